// Round 1
// baseline (326.836 us; speedup 1.0000x reference)
//
#include <hip/hip_runtime.h>

typedef __attribute__((ext_vector_type(8))) short bf16x8;
typedef __attribute__((ext_vector_type(4))) float f32x4;

#define DD 512
#define RR 64
#define BTOT 65536
#define BM 64
#define BK 32

static __device__ __forceinline__ unsigned short f2bf(float f) {
    union { float f; unsigned u; } v; v.f = f;
    unsigned r = v.u + 0x7fffu + ((v.u >> 16) & 1u);
    return (unsigned short)(r >> 16);
}

// ---- Kernel 1: normalize columns of params (D x R) -> U (R x D) fp32 ----
__global__ void normalize_kernel(const float* __restrict__ P, float* __restrict__ U) {
    int i = blockIdx.x;       // reflection index 0..63
    int t = threadIdx.x;      // 0..255
    __shared__ float red[4];
    float a = P[t * RR + i];
    float b = P[(t + 256) * RR + i];
    float p = a * a + b * b;
#pragma unroll
    for (int off = 32; off > 0; off >>= 1) p += __shfl_down(p, off);
    if ((t & 63) == 0) red[t >> 6] = p;
    __syncthreads();
    float s = red[0] + red[1] + red[2] + red[3];
    float inv = 1.0f / sqrtf(s);
    U[i * DD + t]       = a * inv;
    U[i * DD + t + 256] = b * inv;
}

// ---- Kernel 2: compose M = H0 H1 ... H63, store transposed bf16 Mt[n][k] ----
__global__ void compose_kernel(const float* __restrict__ U, unsigned short* __restrict__ Mt) {
    int k = blockIdx.x;   // row of M, 0..511
    int t = threadIdx.x;  // 0..255
    __shared__ float red[4];
    float v0 = (k < 256 && t == k) ? 1.0f : 0.0f;
    float v1 = (k >= 256 && t == (k - 256)) ? 1.0f : 0.0f;
    for (int i = 0; i < RR; ++i) {
        float u0 = U[i * DD + t];
        float u1 = U[i * DD + t + 256];
        float p = v0 * u0 + v1 * u1;
#pragma unroll
        for (int off = 32; off > 0; off >>= 1) p += __shfl_down(p, off);
        if ((t & 63) == 0) red[t >> 6] = p;
        __syncthreads();
        float dot = red[0] + red[1] + red[2] + red[3];
        v0 -= 2.0f * dot * u0;
        v1 -= 2.0f * dot * u1;
        __syncthreads();
    }
    Mt[(size_t)t * DD + k]         = f2bf(v0);
    Mt[(size_t)(t + 256) * DD + k] = f2bf(v1);
}

// ---- Kernel 3: out = x @ M via bf16 MFMA ----
__launch_bounds__(512, 4)
__global__ void gemm_kernel(const float* __restrict__ X,
                            const unsigned short* __restrict__ Mt,
                            float* __restrict__ out) {
    __shared__ __attribute__((aligned(16))) unsigned short lA[BM * BK];   // [m][k]
    __shared__ __attribute__((aligned(16))) unsigned short lB[DD * BK];   // [n][k]
    int t = threadIdx.x;          // 0..511
    int wave = t >> 6, lane = t & 63;
    int quad = lane >> 4, l16 = lane & 15;
    int row0 = blockIdx.x * BM;

    f32x4 acc[4][4] = {};

    int ar = t >> 3;              // 0..63 : A row within tile
    int ak = (t & 7) * 4;         // 0..28 : fp32 offset within BK
    const float* xrow = X + (size_t)(row0 + ar) * DD + ak;

    int bn_lane = lane >> 2;      // 0..15
    int bk_lane = (lane & 3) * 8; // shorts

    for (int k0 = 0; k0 < DD; k0 += BK) {
        // B: global bf16 -> LDS via direct-to-LDS 16B loads (wave-uniform LDS base)
#pragma unroll
        for (int q = 0; q < 4; ++q) {
            int nbase = wave * 64 + q * 16;
            const unsigned short* g = Mt + (size_t)(nbase + bn_lane) * DD + k0 + bk_lane;
            __builtin_amdgcn_global_load_lds(
                (const __attribute__((address_space(1))) unsigned int*)g,
                (__attribute__((address_space(3))) unsigned int*)(lB + nbase * BK),
                16, 0, 0);
        }
        // A: global fp32 -> bf16 -> LDS
        float4 xv = *(const float4*)(xrow + k0);
        ushort4 hv = make_ushort4(f2bf(xv.x), f2bf(xv.y), f2bf(xv.z), f2bf(xv.w));
        *(ushort4*)(lA + ar * BK + ak) = hv;
        __syncthreads();

        bf16x8 afr[4], bfr[4];
#pragma unroll
        for (int mt = 0; mt < 4; ++mt)
            afr[mt] = *(const bf16x8*)(lA + (mt * 16 + l16) * BK + quad * 8);
#pragma unroll
        for (int nt = 0; nt < 4; ++nt)
            bfr[nt] = *(const bf16x8*)(lB + (wave * 64 + nt * 16 + l16) * BK + quad * 8);
#pragma unroll
        for (int mt = 0; mt < 4; ++mt)
#pragma unroll
            for (int nt = 0; nt < 4; ++nt)
                acc[mt][nt] = __builtin_amdgcn_mfma_f32_16x16x32_bf16(afr[mt], bfr[nt], acc[mt][nt], 0, 0, 0);
        __syncthreads();
    }

    // Epilogue: C/D layout col = lane&15, row = quad*4 + r
#pragma unroll
    for (int mt = 0; mt < 4; ++mt) {
#pragma unroll
        for (int r = 0; r < 4; ++r) {
            int row = row0 + mt * 16 + quad * 4 + r;
            float* orow = out + (size_t)row * DD + wave * 64 + l16;
#pragma unroll
            for (int nt = 0; nt < 4; ++nt)
                orow[nt * 16] = acc[mt][nt][r];
        }
    }
}

// ---- Kernel 4: sldj passthrough ----
__global__ void sldj_kernel(const float* __restrict__ s, float* __restrict__ o) {
    int i = blockIdx.x * blockDim.x + threadIdx.x;
    o[i] = s[i];
}

extern "C" void kernel_launch(void* const* d_in, const int* in_sizes, int n_in,
                              void* d_out, int out_size, void* d_ws, size_t ws_size,
                              hipStream_t stream) {
    const float* x      = (const float*)d_in[0];
    const float* sldj   = (const float*)d_in[1];
    const float* params = (const float*)d_in[2];
    float* out = (float*)d_out;

    float* U = (float*)d_ws;                                                   // 64*512 fp32 = 128 KB
    unsigned short* Mt = (unsigned short*)((char*)d_ws + RR * DD * sizeof(float)); // 512*512 bf16 = 512 KB

    normalize_kernel<<<RR, 256, 0, stream>>>(params, U);
    compose_kernel<<<DD, 256, 0, stream>>>(U, Mt);
    gemm_kernel<<<BTOT / BM, 512, 0, stream>>>(x, Mt, out);
    sldj_kernel<<<BTOT / 256, 256, 0, stream>>>(sldj, out + (size_t)BTOT * DD);
}

// Round 2
// 304.222 us; speedup vs baseline: 1.0743x; 1.0743x over previous
//
#include <hip/hip_runtime.h>

typedef __attribute__((ext_vector_type(8))) short bf16x8;
typedef __attribute__((ext_vector_type(4))) float f32x4;

#define DD 512
#define RR 64
#define BTOT 65536
#define BM 128
#define BN 128
#define BK 32

static __device__ __forceinline__ unsigned short f2bf(float f) {
    union { float f; unsigned u; } v; v.f = f;
    unsigned r = v.u + 0x7fffu + ((v.u >> 16) & 1u);
    return (unsigned short)(r >> 16);
}

// ---- Kernel 1: normalize columns of params (D x R) -> U (R x D) fp32 ----
__global__ void normalize_kernel(const float* __restrict__ P, float* __restrict__ U) {
    int i = blockIdx.x;       // reflection index 0..63
    int t = threadIdx.x;      // 0..255
    __shared__ float red[4];
    float a = P[t * RR + i];
    float b = P[(t + 256) * RR + i];
    float p = a * a + b * b;
#pragma unroll
    for (int off = 32; off > 0; off >>= 1) p += __shfl_down(p, off);
    if ((t & 63) == 0) red[t >> 6] = p;
    __syncthreads();
    float s = red[0] + red[1] + red[2] + red[3];
    float inv = 1.0f / sqrtf(s);
    U[i * DD + t]       = a * inv;
    U[i * DD + t + 256] = b * inv;
}

// ---- Kernel 2: compose M = H0..H63, 4 columns per block, store Mt[n][k] bf16 ----
__global__ void compose_kernel(const float* __restrict__ U, unsigned short* __restrict__ Mt) {
    int kb = blockIdx.x * 4;  // first column handled by this block
    int t = threadIdx.x;      // 0..255
    int w = t >> 6;
    __shared__ float red[2][4][4];  // [buf][wave][col]
    float v0[4], v1[4];
#pragma unroll
    for (int c = 0; c < 4; ++c) {
        v0[c] = (kb + c == t) ? 1.0f : 0.0f;
        v1[c] = (kb + c == t + 256) ? 1.0f : 0.0f;
    }
    float u0n = U[t], u1n = U[t + 256];
    for (int i = 0; i < RR; ++i) {
        float u0 = u0n, u1 = u1n;
        if (i + 1 < RR) { u0n = U[(i + 1) * DD + t]; u1n = U[(i + 1) * DD + t + 256]; }
        float p0 = v0[0] * u0 + v1[0] * u1;
        float p1 = v0[1] * u0 + v1[1] * u1;
        float p2 = v0[2] * u0 + v1[2] * u1;
        float p3 = v0[3] * u0 + v1[3] * u1;
#pragma unroll
        for (int off = 32; off > 0; off >>= 1) {
            p0 += __shfl_down(p0, off);
            p1 += __shfl_down(p1, off);
            p2 += __shfl_down(p2, off);
            p3 += __shfl_down(p3, off);
        }
        if ((t & 63) == 0) {
            red[i & 1][w][0] = p0; red[i & 1][w][1] = p1;
            red[i & 1][w][2] = p2; red[i & 1][w][3] = p3;
        }
        __syncthreads();
        float d[4];
#pragma unroll
        for (int c = 0; c < 4; ++c)
            d[c] = red[i & 1][0][c] + red[i & 1][1][c] + red[i & 1][2][c] + red[i & 1][3][c];
#pragma unroll
        for (int c = 0; c < 4; ++c) {
            v0[c] -= 2.0f * d[c] * u0;
            v1[c] -= 2.0f * d[c] * u1;
        }
    }
#pragma unroll
    for (int c = 0; c < 4; ++c) {
        Mt[(size_t)t * DD + kb + c]         = f2bf(v0[c]);
        Mt[(size_t)(t + 256) * DD + kb + c] = f2bf(v1[c]);
    }
}

// ---- Kernel 3: out = x @ M via bf16 MFMA, 128x128 tile, DMA staging, swizzled LDS ----
__launch_bounds__(256, 4)
__global__ void gemm_kernel(const float* __restrict__ X,
                            const unsigned short* __restrict__ Mt,
                            float* __restrict__ out) {
    // lAf: fp32 A-tile [m][k], row = 32 floats = 128B = 8 granules of 16B.
    //      granule slot s holds logical k-granule (s ^ (m&7)).
    // lB : bf16 B-tile [n][k], row = 32 shorts = 64B = 4 granules of 16B.
    //      granule slot s holds logical k-granule (s ^ (n&3)).
    __shared__ __attribute__((aligned(16))) float lAf[BM * BK];          // 16 KB
    __shared__ __attribute__((aligned(16))) unsigned short lB[BN * BK];  // 8 KB

    int t = threadIdx.x;
    int wave = t >> 6, lane = t & 63;
    int wm = wave >> 1, wn = wave & 1;
    int quad = lane >> 4, l16 = lane & 15;
    int row0 = (int)(blockIdx.x >> 2) * BM;
    int col0 = (int)(blockIdx.x & 3) * BN;

    f32x4 acc[4][4] = {};

    // A DMA: issue q covers rows wave*32 + q*8 + (lane>>3); slot granule = lane&7.
    // logical k-granule for this lane = (lane&7) ^ (lane>>3)  (since m&7 == lane>>3)
    int a_kg = (lane & 7) ^ (lane >> 3);
    int a_mrow = wave * 32 + (lane >> 3);         // + q*8
    // B DMA: issue q covers rows wave*32 + q*16 + (lane>>2); slot granule = lane&3.
    int b_kg = (lane & 3) ^ ((lane >> 2) & 3);
    int b_nrow = wave * 32 + (lane >> 2);         // + q*16

    const float* aBase = X + (size_t)(row0 + a_mrow) * DD + a_kg * 4;
    const unsigned short* bBase = Mt + (size_t)(col0 + b_nrow) * DD + b_kg * 8;

#pragma unroll 1
    for (int k0 = 0; k0 < DD; k0 += BK) {
        // stage A (4 issues/wave, fp32 direct-to-LDS)
#pragma unroll
        for (int q = 0; q < 4; ++q) {
            const float* g = aBase + k0 + (size_t)q * 8 * DD;
            __builtin_amdgcn_global_load_lds(
                (const __attribute__((address_space(1))) unsigned int*)g,
                (__attribute__((address_space(3))) unsigned int*)(lAf + (wave * 32 + q * 8) * BK),
                16, 0, 0);
        }
        // stage B (2 issues/wave, bf16 direct-to-LDS)
#pragma unroll
        for (int q = 0; q < 2; ++q) {
            const unsigned short* g = bBase + k0 + (size_t)q * 16 * DD;
            __builtin_amdgcn_global_load_lds(
                (const __attribute__((address_space(1))) unsigned int*)g,
                (__attribute__((address_space(3))) unsigned int*)(lB + (wave * 32 + q * 16) * BK),
                16, 0, 0);
        }
        __syncthreads();

        // B fragments (bf16, swizzled granule = quad ^ (n&3); n&3 == l16&3)
        bf16x8 bfr[4];
#pragma unroll
        for (int nt = 0; nt < 4; ++nt) {
            int n = wn * 64 + nt * 16 + l16;
            bfr[nt] = *(const bf16x8*)(lB + n * BK + (quad ^ (l16 & 3)) * 8);
        }
#pragma unroll
        for (int mt = 0; mt < 4; ++mt) {
            int m = wm * 64 + mt * 16 + l16;
            int s0 = (2 * quad) ^ (l16 & 7);
            int s1 = (2 * quad + 1) ^ (l16 & 7);
            float4 fa0 = *(const float4*)(lAf + m * BK + s0 * 4);
            float4 fa1 = *(const float4*)(lAf + m * BK + s1 * 4);
            bf16x8 afr;
            afr[0] = (short)f2bf(fa0.x); afr[1] = (short)f2bf(fa0.y);
            afr[2] = (short)f2bf(fa0.z); afr[3] = (short)f2bf(fa0.w);
            afr[4] = (short)f2bf(fa1.x); afr[5] = (short)f2bf(fa1.y);
            afr[6] = (short)f2bf(fa1.z); afr[7] = (short)f2bf(fa1.w);
#pragma unroll
            for (int nt = 0; nt < 4; ++nt)
                acc[mt][nt] = __builtin_amdgcn_mfma_f32_16x16x32_bf16(afr, bfr[nt], acc[mt][nt], 0, 0, 0);
        }
        __syncthreads();
    }

    // Epilogue: C/D layout col = lane&15, row = quad*4 + r
#pragma unroll
    for (int mt = 0; mt < 4; ++mt) {
#pragma unroll
        for (int r = 0; r < 4; ++r) {
            int row = row0 + wm * 64 + mt * 16 + quad * 4 + r;
            float* orow = out + (size_t)row * DD + col0 + wn * 64 + l16;
#pragma unroll
            for (int nt = 0; nt < 4; ++nt)
                orow[nt * 16] = acc[mt][nt][r];
        }
    }
}

// ---- Kernel 4: sldj passthrough (vectorized) ----
__global__ void sldj_kernel(const float4* __restrict__ s, float4* __restrict__ o) {
    int i = blockIdx.x * blockDim.x + threadIdx.x;
    o[i] = s[i];
}

extern "C" void kernel_launch(void* const* d_in, const int* in_sizes, int n_in,
                              void* d_out, int out_size, void* d_ws, size_t ws_size,
                              hipStream_t stream) {
    const float* x      = (const float*)d_in[0];
    const float* sldj   = (const float*)d_in[1];
    const float* params = (const float*)d_in[2];
    float* out = (float*)d_out;

    float* U = (float*)d_ws;                                                       // 64*512 fp32 = 128 KB
    unsigned short* Mt = (unsigned short*)((char*)d_ws + RR * DD * sizeof(float)); // 512*512 bf16 = 512 KB

    normalize_kernel<<<RR, 256, 0, stream>>>(params, U);
    compose_kernel<<<DD / 4, 256, 0, stream>>>(U, Mt);
    gemm_kernel<<<(BTOT / BM) * (DD / BN), 256, 0, stream>>>(x, Mt, out);
    sldj_kernel<<<BTOT / 4 / 256, 256, 0, stream>>>((const float4*)sldj,
                                                    (float4*)(out + (size_t)BTOT * DD));
}

// Round 3
// 298.102 us; speedup vs baseline: 1.0964x; 1.0205x over previous
//
#include <hip/hip_runtime.h>

typedef __attribute__((ext_vector_type(8))) short bf16x8;
typedef __attribute__((ext_vector_type(4))) float f32x4;

#define DD 512
#define RR 64
#define BTOT 65536
#define BM 128
#define BN 128
#define BK 32

static __device__ __forceinline__ unsigned short f2bf(float f) {
    union { float f; unsigned u; } v; v.f = f;
    unsigned r = v.u + 0x7fffu + ((v.u >> 16) & 1u);
    return (unsigned short)(r >> 16);
}

// pack two fp32 -> two bf16 (round-half-up) in one v_perm
static __device__ __forceinline__ unsigned pack2bf(float x, float y) {
    union { float f; unsigned u; } a, b;
    a.f = x; b.f = y;
    unsigned ax = a.u + 0x8000u, bx = b.u + 0x8000u;
    return __builtin_amdgcn_perm(bx, ax, 0x07060302u);
}

// ---- Kernel 1: normalize columns of params (D x R) -> U (R x D) fp32 ----
__global__ void normalize_kernel(const float* __restrict__ P, float* __restrict__ U) {
    int i = blockIdx.x;       // reflection index 0..63
    int t = threadIdx.x;      // 0..255
    __shared__ float red[4];
    float a = P[t * RR + i];
    float b = P[(t + 256) * RR + i];
    float p = a * a + b * b;
#pragma unroll
    for (int off = 32; off > 0; off >>= 1) p += __shfl_down(p, off);
    if ((t & 63) == 0) red[t >> 6] = p;
    __syncthreads();
    float s = red[0] + red[1] + red[2] + red[3];
    float inv = 1.0f / sqrtf(s);
    U[i * DD + t]       = a * inv;
    U[i * DD + t + 256] = b * inv;
}

// ---- Kernel 2: compose M = H0..H63, 4 columns per block, store Mt[n][k] bf16 ----
__global__ void compose_kernel(const float* __restrict__ U, unsigned short* __restrict__ Mt) {
    int kb = blockIdx.x * 4;  // first column handled by this block
    int t = threadIdx.x;      // 0..255
    int w = t >> 6;
    __shared__ float red[2][4][4];  // [buf][wave][col]
    float v0[4], v1[4];
#pragma unroll
    for (int c = 0; c < 4; ++c) {
        v0[c] = (kb + c == t) ? 1.0f : 0.0f;
        v1[c] = (kb + c == t + 256) ? 1.0f : 0.0f;
    }
    float u0n = U[t], u1n = U[t + 256];
    for (int i = 0; i < RR; ++i) {
        float u0 = u0n, u1 = u1n;
        if (i + 1 < RR) { u0n = U[(i + 1) * DD + t]; u1n = U[(i + 1) * DD + t + 256]; }
        float p0 = v0[0] * u0 + v1[0] * u1;
        float p1 = v0[1] * u0 + v1[1] * u1;
        float p2 = v0[2] * u0 + v1[2] * u1;
        float p3 = v0[3] * u0 + v1[3] * u1;
#pragma unroll
        for (int off = 32; off > 0; off >>= 1) {
            p0 += __shfl_down(p0, off);
            p1 += __shfl_down(p1, off);
            p2 += __shfl_down(p2, off);
            p3 += __shfl_down(p3, off);
        }
        if ((t & 63) == 0) {
            red[i & 1][w][0] = p0; red[i & 1][w][1] = p1;
            red[i & 1][w][2] = p2; red[i & 1][w][3] = p3;
        }
        __syncthreads();
        float d[4];
#pragma unroll
        for (int c = 0; c < 4; ++c)
            d[c] = red[i & 1][0][c] + red[i & 1][1][c] + red[i & 1][2][c] + red[i & 1][3][c];
#pragma unroll
        for (int c = 0; c < 4; ++c) {
            v0[c] -= 2.0f * d[c] * u0;
            v1[c] -= 2.0f * d[c] * u1;
        }
    }
#pragma unroll
    for (int c = 0; c < 4; ++c) {
        Mt[(size_t)t * DD + kb + c]         = f2bf(v0[c]);
        Mt[(size_t)(t + 256) * DD + kb + c] = f2bf(v1[c]);
    }
}

// ---- Kernel 3: out = x @ M, 128x128 tile, DMA staging, XCD-aware tile map ----
__launch_bounds__(256, 4)
__global__ void gemm_kernel(const float* __restrict__ X,
                            const unsigned short* __restrict__ Mt,
                            const float* __restrict__ sldj,
                            float* __restrict__ out) {
    __shared__ __attribute__((aligned(16))) float lAf[BM * BK];          // 16 KB
    __shared__ __attribute__((aligned(16))) unsigned short lB[BN * BK];  // 8 KB

    int t = threadIdx.x;
    int bid = blockIdx.x;

    // fold sldj copy into the first 64 blocks (256 KB total)
    if (bid < 64) {
        const float4* s4 = (const float4*)sldj;
        float4* o4 = (float4*)(out + (size_t)BTOT * DD);
        o4[bid * 256 + t] = s4[bid * 256 + t];
    }

    // XCD-aware remap: blocks {32g + 8c + x | c=0..3} are consecutive slots on
    // XCD x (dispatch is bid%8 round-robin) and share one A row-tile -> L2 reuse.
    int row_t = (bid >> 5) * 8 + (bid & 7);   // 0..511
    int col_t = (bid >> 3) & 3;               // 0..3
    int row0 = row_t * BM;
    int col0 = col_t * BN;

    int wave = t >> 6, lane = t & 63;
    int wm = wave >> 1, wn = wave & 1;
    int quad = lane >> 4, l16 = lane & 15;

    f32x4 acc[4][4] = {};

    // A DMA: issue q covers rows wave*32 + q*8 + (lane>>3); slot granule = lane&7.
    int a_kg = (lane & 7) ^ (lane >> 3);
    int a_mrow = wave * 32 + (lane >> 3);
    // B DMA: issue q covers rows wave*32 + q*16 + (lane>>2); slot granule = lane&3.
    int b_kg = (lane & 3) ^ ((lane >> 2) & 3);
    int b_nrow = wave * 32 + (lane >> 2);

    const float* aBase = X + (size_t)(row0 + a_mrow) * DD + a_kg * 4;
    const unsigned short* bBase = Mt + (size_t)(col0 + b_nrow) * DD + b_kg * 8;

#pragma unroll 1
    for (int k0 = 0; k0 < DD; k0 += BK) {
#pragma unroll
        for (int q = 0; q < 4; ++q) {
            const float* g = aBase + k0 + (size_t)q * 8 * DD;
            __builtin_amdgcn_global_load_lds(
                (const __attribute__((address_space(1))) unsigned int*)g,
                (__attribute__((address_space(3))) unsigned int*)(lAf + (wave * 32 + q * 8) * BK),
                16, 0, 0);
        }
#pragma unroll
        for (int q = 0; q < 2; ++q) {
            const unsigned short* g = bBase + k0 + (size_t)q * 16 * DD;
            __builtin_amdgcn_global_load_lds(
                (const __attribute__((address_space(1))) unsigned int*)g,
                (__attribute__((address_space(3))) unsigned int*)(lB + (wave * 32 + q * 16) * BK),
                16, 0, 0);
        }
        __syncthreads();

        bf16x8 bfr[4];
#pragma unroll
        for (int nt = 0; nt < 4; ++nt) {
            int n = wn * 64 + nt * 16 + l16;
            bfr[nt] = *(const bf16x8*)(lB + n * BK + (quad ^ (l16 & 3)) * 8);
        }
#pragma unroll
        for (int mt = 0; mt < 4; ++mt) {
            int m = wm * 64 + mt * 16 + l16;
            int s0 = (2 * quad) ^ (l16 & 7);
            int s1 = (2 * quad + 1) ^ (l16 & 7);
            float4 fa0 = *(const float4*)(lAf + m * BK + s0 * 4);
            float4 fa1 = *(const float4*)(lAf + m * BK + s1 * 4);
            union { unsigned u[4]; bf16x8 v; } afr;
            afr.u[0] = pack2bf(fa0.x, fa0.y);
            afr.u[1] = pack2bf(fa0.z, fa0.w);
            afr.u[2] = pack2bf(fa1.x, fa1.y);
            afr.u[3] = pack2bf(fa1.z, fa1.w);
#pragma unroll
            for (int nt = 0; nt < 4; ++nt)
                acc[mt][nt] = __builtin_amdgcn_mfma_f32_16x16x32_bf16(afr.v, bfr[nt], acc[mt][nt], 0, 0, 0);
        }
        __syncthreads();
    }

    // Epilogue: C/D layout col = lane&15, row = quad*4 + r
#pragma unroll
    for (int mt = 0; mt < 4; ++mt) {
#pragma unroll
        for (int r = 0; r < 4; ++r) {
            int row = row0 + wm * 64 + mt * 16 + quad * 4 + r;
            float* orow = out + (size_t)row * DD + col0 + wn * 64 + l16;
#pragma unroll
            for (int nt = 0; nt < 4; ++nt)
                orow[nt * 16] = acc[mt][nt][r];
        }
    }
}

extern "C" void kernel_launch(void* const* d_in, const int* in_sizes, int n_in,
                              void* d_out, int out_size, void* d_ws, size_t ws_size,
                              hipStream_t stream) {
    const float* x      = (const float*)d_in[0];
    const float* sldj   = (const float*)d_in[1];
    const float* params = (const float*)d_in[2];
    float* out = (float*)d_out;

    float* U = (float*)d_ws;                                                       // 64*512 fp32 = 128 KB
    unsigned short* Mt = (unsigned short*)((char*)d_ws + RR * DD * sizeof(float)); // 512*512 bf16 = 512 KB

    normalize_kernel<<<RR, 256, 0, stream>>>(params, U);
    compose_kernel<<<DD / 4, 256, 0, stream>>>(U, Mt);
    gemm_kernel<<<(BTOT / BM) * (DD / BN), 256, 0, stream>>>(x, Mt, sldj, out);
}